// Round 6
// baseline (268.530 us; speedup 1.0000x reference)
//
#include <hip/hip_runtime.h>

// ExpandEvecs: out[b][k][n][m] = sum_{j<=k} e[b][n][j] * e[b][m][j]
// B=4, C=1, N=1024, K=16. fp32 in / fp32 out. Write-BW-bound (268 MB out).
// Kernel-only time ~95 us (bench dur includes constant ~162 us harness fill)
// = 2.8 TB/s effective vs 6.6 TB/s fill ceiling -> L2 dirty-drain theory.
// R6: same as R5 but with a native ext_vector float4 so
// __builtin_nontemporal_store compiles (HIP_vector_type is rejected).

#define BB 4
#define NN 1024
#define KK 16
#define ROWS 8

typedef float f32x4 __attribute__((ext_vector_type(4)));

__global__ __launch_bounds__(256) void ExpandEvecs_75780402970966_kernel(
    const float* __restrict__ ev,   // [B][N][K] float32
    float* __restrict__ out)        // [B][K][N][N] float32
{
    const int tid = threadIdx.x;
    const int m0  = tid << 2;                 // 256 threads x 4 m = all 1024 m
    const int grp = blockIdx.x & 127;         // n-group within b
    const int b   = blockIdx.x >> 7;
    const int n0  = grp * ROWS;

    const float* eb = ev + (size_t)b * NN * KK;   // this batch's slab (64 KiB)

    float acc[ROWS][4];
#pragma unroll
    for (int r = 0; r < ROWS; ++r)
#pragma unroll
        for (int v = 0; v < 4; ++v) acc[r][v] = 0.0f;

    const size_t kplane = (size_t)NN * NN;
    const size_t obase  = (size_t)b * KK * kplane + (size_t)n0 * NN + (size_t)m0;

#pragma unroll
    for (int kb = 0; kb < KK / 4; ++kb) {          // k in blocks of 4
        f32x4 em4[4];                               // this thread's 4 m-rows
#pragma unroll
        for (int v = 0; v < 4; ++v)
            em4[v] = *(const f32x4*)(eb + (size_t)(m0 + v) * KK + kb * 4);

        f32x4 en4[ROWS];                            // block-uniform -> s_load
#pragma unroll
        for (int r = 0; r < ROWS; ++r)
            en4[r] = *(const f32x4*)(eb + (size_t)(n0 + r) * KK + kb * 4);

#pragma unroll
        for (int kk = 0; kk < 4; ++kk) {
            const int k = kb * 4 + kk;
            float* outk = out + obase + (size_t)k * kplane;
#pragma unroll
            for (int r = 0; r < ROWS; ++r) {
                const float enk = en4[r][kk];
#pragma unroll
                for (int v = 0; v < 4; ++v)
                    acc[r][v] = fmaf(em4[v][kk], enk, acc[r][v]);
                f32x4 st;
                st.x = acc[r][0]; st.y = acc[r][1];
                st.z = acc[r][2]; st.w = acc[r][3];
                __builtin_nontemporal_store(st, (f32x4*)(outk + (size_t)r * NN));
            }
        }
    }
}

extern "C" void kernel_launch(void* const* d_in, const int* in_sizes, int n_in,
                              void* d_out, int out_size, void* d_ws, size_t ws_size,
                              hipStream_t stream) {
    const float* ev = (const float*)d_in[0];
    float* out = (float*)d_out;

    const int grid = BB * (NN / ROWS);   // 512 blocks, 256 threads
    ExpandEvecs_75780402970966_kernel<<<grid, 256, 0, stream>>>(ev, out);
}